// Round 1
// baseline (246.882 us; speedup 1.0000x reference)
//
#include <hip/hip_runtime.h>
#include <stdint.h>

// Disable FMA contraction file-wide: we must replicate the reference's
// per-op f32 rounding (decode + IoU) to avoid NMS decision flips.
#pragma clang fp contract(off)

#define B_IMGS   4
#define NLVL     5
#define A_TOTAL  242991
#define NSEL     4741          // 1000*4 + 741
#define NBUCK    8192          // 13-bit buckets: sign+exp+4 mantissa (os>>19)
#define BSHIFT   19
#define CAND_CAP 2048
#define POST_NMS 1000
#define NBL      (B_IMGS * NLVL)
#define NMS_TH   0.7f
#define NEGV     (-1e10f)
#define W_IMGF   1216.0f
#define H_IMGF   800.0f
#define MIN_SZ   1e-3f
#define BBOX_CLIP 4.135166556742356f   // log(1000/16)

// Fused-kernel geometry: 136 blocks x 512 threads. 136 <= 256 CUs and
// __launch_bounds__(512,2) caps VGPR<=256 -> every block fits a CU ->
// all blocks co-resident -> grid barrier is safe (guide §1 manual regime).
#define NBLK     136
#define BLKT     512
#define HBLK_PER_IMG 34

// ---------- level helpers ----------
__device__ __forceinline__ int lvl_k(int l) { return (l == 4) ? 741 : 1000; }

// per-image 34-block span decomposition (same as the verified k_hist)
__device__ __forceinline__ void span34(int r, int& l, int& sub, int& chunk,
                                       int& lstart, int& n) {
    if (r < 24)      { l = 0; sub = r;      chunk = 7600; lstart = 0;      n = 182400; }
    else if (r < 30) { l = 1; sub = r - 24; chunk = 7600; lstart = 182400; n = 45600; }
    else if (r < 32) { l = 2; sub = r - 30; chunk = 5700; lstart = 228000; n = 11400; }
    else if (r == 32){ l = 3; sub = 0;      chunk = 2850; lstart = 239400; n = 2850; }
    else             { l = 4; sub = 0;      chunk = 741;  lstart = 242250; n = 741; }
}

// ---------- order-preserving float<->uint ----------
__device__ __forceinline__ unsigned flipf(float f) {
    unsigned u = __float_as_uint(f);
    return u ^ (unsigned)(((int)u >> 31) | 0x80000000);
}
__device__ __forceinline__ float unflipf(unsigned os) {
    unsigned u = (os & 0x80000000u) ? (os ^ 0x80000000u) : ~os;
    return __uint_as_float(u);
}

// ---------- async global->LDS DMA (16B per lane, wave-uniform LDS base) ----------
__device__ __forceinline__ void async_cp16(const void* g, void* l) {
    __builtin_amdgcn_global_load_lds(
        (const __attribute__((address_space(1))) unsigned*)g,
        (__attribute__((address_space(3))) unsigned*)l,
        16, 0, 0);
}

// ---------- binary search in LDS: #elements < key ----------
__device__ __forceinline__ int lbound_lds(const unsigned long long* s, int len,
                                          unsigned long long key) {
    int lo = 0, hi = len;
    while (lo < hi) {
        int mid = (lo + hi) >> 1;
        if (s[mid] < key) lo = mid + 1; else hi = mid;
    }
    return lo;
}

// ---------- grid barrier (monotonic counter; agent-scope fences handle
// cross-XCD L2 non-coherence: release-writeback before arrive, acquire-
// invalidate after release) ----------
__device__ __forceinline__ void gbar(unsigned* bar, unsigned target) {
    __syncthreads();                       // all waves' stores drained (vmcnt)
    if (threadIdx.x == 0) {
        __threadfence();                   // agent release: writeback L2
        __hip_atomic_fetch_add(bar, 1u, __ATOMIC_RELAXED, __HIP_MEMORY_SCOPE_AGENT);
        while (__hip_atomic_load(bar, __ATOMIC_RELAXED, __HIP_MEMORY_SCOPE_AGENT) < target)
            __builtin_amdgcn_s_sleep(8);
        __threadfence();                   // agent acquire: invalidate L1/L2
    }
    __syncthreads();
}

// ---------- workspace layout ----------
static constexpr size_t SZ_HIST    = (size_t)NBL * NBUCK * sizeof(unsigned);        // 655,360
static constexpr size_t OFF_CNT    = SZ_HIST;                                        // +80
static constexpr size_t OFF_BOXMAX = OFF_CNT + NBL * sizeof(unsigned);               // +16
static constexpr size_t OFF_BAR    = OFF_BOXMAX + B_IMGS * sizeof(unsigned);         // +4 (pad to 16)
static constexpr size_t ZERO_BYTES = OFF_BAR + 16;
static constexpr size_t OFF_CAND   = (ZERO_BYTES + 15) & ~(size_t)15;
static constexpr size_t OFF_SEL    = OFF_CAND + (size_t)NBL * CAND_CAP * 8;
static constexpr size_t OFF_BOXR   = OFF_SEL + (size_t)B_IMGS * NSEL * 8;
static constexpr size_t OFF_SCR    = OFF_BOXR + (size_t)B_IMGS * NSEL * 16;
static constexpr size_t OFF_BOXL   = OFF_SCR + (size_t)B_IMGS * NSEL * 4;
static constexpr size_t OFF_VAL    = OFF_BOXL + (size_t)B_IMGS * NSEL * 16;
static constexpr size_t OFF_RMAP   = OFF_VAL + (size_t)B_IMGS * NSEL * 4;
static constexpr size_t OFF_KEEP   = OFF_RMAP + (size_t)B_IMGS * NSEL * 4;
static constexpr size_t OFF_MASK   = OFF_KEEP + (size_t)B_IMGS * NSEL * 4;           // 16-aligned
static constexpr size_t WS_NEED    = OFF_MASK + (size_t)NBL * 1024 * 16 * 8;         // ~4.7 MB

// ---------- the fused pipeline ----------
// Phases (identical math to the verified 7-kernel version, remapped to 136x512):
//   A hist | B compact | C sort | D decode | E mask | F resolve | G output
__global__ __launch_bounds__(BLKT, 2) void k_fused(
    const float* __restrict__ obj, const float* __restrict__ deltas,
    const float* __restrict__ anchors,
    unsigned* __restrict__ hist, unsigned* __restrict__ cnt,
    unsigned* __restrict__ boxmax, unsigned* __restrict__ bar,
    unsigned long long* __restrict__ cand, unsigned long long* __restrict__ sel,
    float* __restrict__ boxes_r, float* __restrict__ score_r,
    float* __restrict__ boxes_l, int* __restrict__ valid_l,
    int* __restrict__ rankmap, int* __restrict__ keep_r,
    unsigned long long* __restrict__ maskp, float* __restrict__ out)
{
    __shared__ __align__(16) char smem[38912];   // union across phases (max = D: 37,960 B)
    const int tid = threadIdx.x;
    const int bid = blockIdx.x;

    // ================= Phase A: per-(b,level) LDS histogram =================
    {
        unsigned* lh = (unsigned*)smem;                       // 32 KB
        const int b = bid / HBLK_PER_IMG;
        const int r = bid - b * HBLK_PER_IMG;
        int l, sub, chunk, lstart, n;
        span34(r, l, sub, chunk, lstart, n);
        for (int i = tid; i < NBUCK; i += BLKT) lh[i] = 0;
        __syncthreads();
        const int s0 = sub * chunk;
        const int m = min(chunk, n - s0);
        const float* src = obj + (size_t)b * A_TOTAL + lstart + s0;
        for (int i = tid; i < m; i += BLKT) {
            unsigned os = flipf(src[i]);
            atomicAdd(&lh[os >> BSHIFT], 1u);
        }
        __syncthreads();
        unsigned* gh = hist + (size_t)(b * NLVL + l) * NBUCK;
        for (int i = tid; i < NBUCK; i += BLKT) {
            unsigned v = lh[i];
            if (v) atomicAdd(&gh[i], v);
        }
    }
    gbar(bar, 1u * NBLK);

    // ================= Phase B: threshold + compact candidates =================
    {
        unsigned long long* sbuf = (unsigned long long*)smem;   // 16,384
        unsigned* part     = (unsigned*)(smem + 16384);         // 1,024
        unsigned* chunkbuf = (unsigned*)(smem + 17408);         // 128
        int*      s_chunk  = (int*)     (smem + 17536);
        unsigned* s_cum    = (unsigned*)(smem + 17540);
        unsigned* s_thr    = (unsigned*)(smem + 17544);
        unsigned* lcnt     = (unsigned*)(smem + 17548);
        unsigned* gbase    = (unsigned*)(smem + 17552);
        const int b = bid / HBLK_PER_IMG;
        const int r = bid - b * HBLK_PER_IMG;
        int l, sub, chunk, lstart, n;
        span34(r, l, sub, chunk, lstart, n);
        const int bl = b * NLVL + l;
        const int kl = lvl_k(l);
        const unsigned* h = hist + (size_t)bl * NBUCK;
        if (tid < 256) {
            unsigned s = 0;
            for (int i = 0; i < 32; ++i) s += h[tid * 32 + i];
            part[tid] = s;
        }
        if (tid == 0) *lcnt = 0;
        __syncthreads();
        if (tid == 0) {
            unsigned cum = 0;
            int t = 255;
            for (; t > 0; --t) {
                if (cum + part[t] >= (unsigned)kl) break;
                cum += part[t];
            }
            *s_chunk = t;
            *s_cum = cum;
        }
        __syncthreads();
        if (tid < 32) chunkbuf[tid] = h[(*s_chunk) * 32 + tid];
        __syncthreads();
        if (tid == 0) {
            unsigned c2 = *s_cum;
            int T = (*s_chunk) * 32;
            for (int i = 31; i >= 0; --i) {
                c2 += chunkbuf[i];
                if (c2 >= (unsigned)kl) { T = (*s_chunk) * 32 + i; break; }
            }
            *s_thr = (unsigned)T;
        }
        __syncthreads();
        const unsigned T = *s_thr;
        const int s0 = sub * chunk;
        const int m = min(chunk, n - s0);
        const int abase = lstart + s0;
        const float* src = obj + (size_t)b * A_TOTAL + abase;
        for (int i = tid; i < m; i += BLKT) {
            unsigned os = flipf(src[i]);
            if ((os >> BSHIFT) >= T) {
                unsigned slot = atomicAdd(lcnt, 1u);
                if (slot < CAND_CAP)
                    sbuf[slot] = (((unsigned long long)(~os)) << 32) | (unsigned)(abase + i);
            }
        }
        __syncthreads();
        unsigned total = *lcnt; if (total > CAND_CAP) total = CAND_CAP;
        if (tid == 0) *gbase = atomicAdd(&cnt[bl], total);
        __syncthreads();
        const unsigned gb = *gbase;
        for (unsigned i = tid; i < total; i += BLKT) {
            unsigned g = gb + i;
            if (g < CAND_CAP)
                cand[(size_t)bl * CAND_CAP + g] = sbuf[i];
        }
    }
    gbar(bar, 2u * NBLK);

    // ================= Phase C: per-(b,level) bitonic sort =================
    if (bid < NBL) {
        unsigned long long* keys = (unsigned long long*)smem;   // 16 KB
        const int bl = bid;
        const int b = bl / NLVL, l = bl - b * NLVL;
        int m = (int)cnt[bl];
        if (m > CAND_CAP) m = CAND_CAP;
        for (int i = tid; i < CAND_CAP; i += BLKT)
            keys[i] = (i < m) ? cand[(size_t)bl * CAND_CAP + i] : ~0ULL;
        __syncthreads();
        for (int k = 2; k <= CAND_CAP; k <<= 1) {
            for (int j = k >> 1; j > 0; j >>= 1) {
                for (int t = tid; t < CAND_CAP / 2; t += BLKT) {
                    int i = ((t / j) * (j << 1)) + (t % j);
                    int p = i + j;
                    bool up = ((i & k) == 0);
                    unsigned long long a = keys[i], c = keys[p];
                    if ((a > c) == up) { keys[i] = c; keys[p] = a; }
                }
                __syncthreads();
            }
        }
        int kl = lvl_k(l);
        for (int q = tid; q < kl; q += BLKT)
            sel[(size_t)b * NSEL + l * 1000 + q] = keys[q];
    }
    gbar(bar, 3u * NBLK);

    // ================= Phase D: decode + clip + global rank =================
    if (bid < B_IMGS * 10) {
        unsigned long long* skey = (unsigned long long*)smem;   // 37,928 B
        float* wmax = (float*)(smem + 37928);                   // 8 floats
        const int b = bid / 10;
        const int sub = bid - b * 10;
        for (int i = tid; i < NSEL; i += BLKT)
            skey[i] = sel[(size_t)b * NSEL + i];
        __syncthreads();

        int p = sub * BLKT + tid;
        bool on = p < NSEL;
        float mx = 0.0f;
        if (on) {
            int l = p / 1000;           // p in [4000,4741) -> 4
            int q = p - l * 1000;
            unsigned long long key = skey[p];
            unsigned a = (unsigned)(key & 0xFFFFFFFFu);
            unsigned os = ~((unsigned)(key >> 32));
            if (a >= A_TOTAL) a = 0;    // impossible-path safety (MAX padding)
            float score = unflipf(os);
            // global rank = q + sum over other levels of (#keys < key)
            int r = q;
            for (int l2 = 0; l2 < NLVL; ++l2) {
                if (l2 == l) continue;
                r += lbound_lds(skey + l2 * 1000, lvl_k(l2), key);
            }
            // decode (replicates reference op order; contraction disabled)
            const float* dv = deltas + ((size_t)b * A_TOTAL + a) * 4;
            const float* av = anchors + (size_t)a * 4;
            float ax1 = av[0], ay1 = av[1], ax2 = av[2], ay2 = av[3];
            float wa = ax2 - ax1, ha = ay2 - ay1;
            float cxa = ax1 + 0.5f * wa, cya = ay1 + 0.5f * ha;
            float dx = dv[0], dy = dv[1];
            float dw = fminf(dv[2], BBOX_CLIP), dh = fminf(dv[3], BBOX_CLIP);
            float cx = dx * wa + cxa, cy = dy * ha + cya;
            float w = expf(dw) * wa, h = expf(dh) * ha;
            float x1 = cx - 0.5f * w, y1 = cy - 0.5f * h;
            float x2 = cx + 0.5f * w, y2 = cy + 0.5f * h;
            float x1c = fminf(fmaxf(x1, 0.0f), W_IMGF);
            float y1c = fminf(fmaxf(y1, 0.0f), H_IMGF);
            float x2c = fminf(fmaxf(x2, 0.0f), W_IMGF);
            float y2c = fminf(fmaxf(y2, 0.0f), H_IMGF);
            int valid = ((x2c - x1c) >= MIN_SZ) && ((y2c - y1c) >= MIN_SZ);
            mx = fmaxf(fmaxf(x1c, y1c), fmaxf(x2c, y2c));
            size_t rp = (size_t)b * NSEL + r;
            boxes_r[rp * 4 + 0] = x1c; boxes_r[rp * 4 + 1] = y1c;
            boxes_r[rp * 4 + 2] = x2c; boxes_r[rp * 4 + 3] = y2c;
            score_r[rp] = score;
            size_t pp = (size_t)b * NSEL + p;
            boxes_l[pp * 4 + 0] = x1c; boxes_l[pp * 4 + 1] = y1c;
            boxes_l[pp * 4 + 2] = x2c; boxes_l[pp * 4 + 3] = y2c;
            valid_l[pp] = valid;
            rankmap[pp] = r;
        }
        // block max -> single device atomic (coords >= 0: bit order == value order)
        #pragma unroll
        for (int o = 32; o > 0; o >>= 1)
            mx = fmaxf(mx, __shfl_xor(mx, o));
        if ((tid & 63) == 0) wmax[tid >> 6] = mx;
        __syncthreads();
        if (tid == 0) {
            float m2 = wmax[0];
            #pragma unroll
            for (int i = 1; i < 8; ++i) m2 = fmaxf(m2, wmax[i]);
            atomicMax(boxmax + b, __float_as_uint(m2));
        }
    }
    gbar(bar, 4u * NBLK);

    // ================= Phase E: suppression bitmask =================
    // 640 units: (w in 0..15) x (rg2 in 0..1, 512 rows) x (bl in 0..19)
    {
        float (*cb)[5] = (float(*)[5])smem;     // 1,280 B
        for (int u = bid; u < 640; u += NBLK) {
            int w = u & 15, rg2 = (u >> 4) & 1, bl = u >> 5;
            int b = bl / NLVL, l = bl - b * NLVL;
            int kl = lvl_k(l);
            bool act = (rg2 * BLKT < kl);
            float M = __uint_as_float(boxmax[b]) + 1.0f;
            float off = (float)l * M;
            int j0 = w * 64;
            __syncthreads();                    // protect cb reuse across units
            if (act && tid < 64) {
                int j = j0 + tid;
                if (j < kl) {
                    const float* bp = boxes_l + ((size_t)b * NSEL + l * 1000 + j) * 4;
                    float x1 = bp[0] + off, y1 = bp[1] + off;
                    float x2 = bp[2] + off, y2 = bp[3] + off;
                    cb[tid][0] = x1; cb[tid][1] = y1; cb[tid][2] = x2; cb[tid][3] = y2;
                    cb[tid][4] = (x2 - x1) * (y2 - y1);
                }
            }
            __syncthreads();
            int i = rg2 * BLKT + tid;
            if (act && i < kl) {
                unsigned long long word = 0;
                if (j0 + 63 > i) {
                    const float* bp = boxes_l + ((size_t)b * NSEL + l * 1000 + i) * 4;
                    float ix1 = bp[0] + off, iy1 = bp[1] + off;
                    float ix2 = bp[2] + off, iy2 = bp[3] + off;
                    float ai = (ix2 - ix1) * (iy2 - iy1);
                    int jmax = min(64, kl - j0);
                    for (int bb = 0; bb < jmax; ++bb) {
                        int jj = j0 + bb;
                        if (jj <= i) continue;
                        float ltx = fmaxf(ix1, cb[bb][0]), lty = fmaxf(iy1, cb[bb][1]);
                        float rbx = fminf(ix2, cb[bb][2]), rby = fminf(iy2, cb[bb][3]);
                        float ww = fmaxf(rbx - ltx, 0.0f), hh = fmaxf(rby - lty, 0.0f);
                        float inter = ww * hh;
                        float iou = inter / ((ai + cb[bb][4]) - inter);
                        if (iou > NMS_TH) word |= (1ULL << bb);
                    }
                }
                maskp[((size_t)bl * 1024 + i) * 16 + w] = word;
            }
        }
    }
    gbar(bar, 5u * NBLK);

    // ================= Phase F: sequential greedy resolve (wave 0) =================
    if (bid < NBL) {
        const int bl = bid;
        const int b = bl / NLVL, l = bl - b * NLVL;
        const int kl = lvl_k(l);
        const int lane = tid;                    // used under tid<64 guard only
        unsigned long long* sA = (unsigned long long*)smem;           // 8 KB
        unsigned long long* sB = (unsigned long long*)(smem + 8192);  // 8 KB
        const int base = b * NSEL + l * 1000;
        unsigned long long keep_w = 0;
        const int nch = (kl + 63) >> 6;          // 16 or 12
        const char* mbyte = (const char*)(maskp + (size_t)bl * 1024 * 16);

        if (tid < 64) {
            for (int c = 0; c < 16; ++c) {
                int q = c * 64 + lane;
                int vv = (q < kl) ? valid_l[base + q] : 0;
                unsigned long long bm = __ballot(vv);
                if (lane == c) keep_w = bm;
            }
            const char* g0 = mbyte + (size_t)lane * 16;
            #pragma unroll
            for (int j = 0; j < 8; ++j)
                async_cp16(g0 + j * 1024, (char*)sA + j * 1024);
        }
        for (int c = 0; c < nch; ++c) {
            __syncthreads();                     // wave0 drains vmcnt: chunk c staged
            if (tid < 64) {
                unsigned long long* cur = (c & 1) ? sB : sA;
                unsigned long long* nxt = (c & 1) ? sA : sB;
                if (c + 1 < nch) {
                    const char* g1 = mbyte + (size_t)(c + 1) * 8192 + (size_t)lane * 16;
                    #pragma unroll
                    for (int j = 0; j < 8; ++j)
                        async_cp16(g1 + j * 1024, (char*)nxt + j * 1024);
                }
                unsigned long long kw = __shfl(keep_w, c);   // uniform
                if (kw) {
                    unsigned long long diag = cur[lane * 16 + c];
                    unsigned dlo = (unsigned)diag, dhi = (unsigned)(diag >> 32);
                    unsigned long long nz = __ballot(diag != 0ULL);
                    unsigned long long rem = kw & nz;
                    while (rem) {
                        int rr = __ffsll((long long)rem) - 1;
                        unsigned lo = __builtin_amdgcn_readlane(dlo, rr);
                        unsigned hi = __builtin_amdgcn_readlane(dhi, rr);
                        unsigned long long d = ((unsigned long long)hi << 32) | lo;
                        kw &= ~d;
                        rem &= ~(d | (1ULL << rr));
                    }
                    unsigned long long supp = 0;
                    if (lane < 16) {
                        #pragma unroll
                        for (int rr = 0; rr < 64; ++rr) {
                            unsigned long long mm = cur[rr * 16 + lane];
                            supp |= (((kw >> rr) & 1ULL) ? mm : 0ULL);
                        }
                    }
                    if (lane == c) keep_w = kw;
                    else if (lane < 16 && lane > c) keep_w &= ~supp;
                }
            }
        }
        __syncthreads();
        if (tid < 64) {
            for (int c = 0; c < 16; ++c) {
                unsigned long long kwc = __shfl(keep_w, c);
                int q = c * 64 + lane;
                if (q < kl)
                    keep_r[b * NSEL + rankmap[base + q]] = (int)((kwc >> lane) & 1ULL);
            }
        }
    }
    gbar(bar, 6u * NBLK);

    // ================= Phase G: compact kept entries into output =================
    if (bid < B_IMGS) {
        int* ps = (int*)smem;                    // 2 KB
        const int b = bid;
        float* ob = out + (size_t)b * POST_NMS * 4;
        float* osc = out + (size_t)B_IMGS * POST_NMS * 4 + (size_t)b * POST_NMS;
        for (int p = tid; p < POST_NMS; p += BLKT) {
            ob[p * 4 + 0] = 0.0f; ob[p * 4 + 1] = 0.0f;
            ob[p * 4 + 2] = 0.0f; ob[p * 4 + 3] = 0.0f;
            osc[p] = NEGV;
        }
        __syncthreads();   // global writes drained before barrier (vmcnt)
        const int CH = 10;  // 10*512 = 5120 >= 4741
        int basei = tid * CH;
        int c0 = 0;
        #pragma unroll
        for (int k = 0; k < CH; ++k) {
            int rr = basei + k;
            if (rr < NSEL) c0 += keep_r[b * NSEL + rr];
        }
        ps[tid] = c0;
        __syncthreads();
        for (int ofs = 1; ofs < BLKT; ofs <<= 1) {
            int v = (tid >= ofs) ? ps[tid - ofs] : 0;
            __syncthreads();
            ps[tid] += v;
            __syncthreads();
        }
        int p = ps[tid] - c0;   // exclusive prefix
        #pragma unroll
        for (int k = 0; k < CH; ++k) {
            int rr = basei + k;
            if (rr < NSEL && keep_r[b * NSEL + rr]) {
                if (p < POST_NMS) {
                    const float* bp = boxes_r + ((size_t)b * NSEL + rr) * 4;
                    ob[p * 4 + 0] = bp[0]; ob[p * 4 + 1] = bp[1];
                    ob[p * 4 + 2] = bp[2]; ob[p * 4 + 3] = bp[3];
                    osc[p] = score_r[(size_t)b * NSEL + rr];
                }
                ++p;
            }
        }
    }
}

extern "C" void kernel_launch(void* const* d_in, const int* in_sizes, int n_in,
                              void* d_out, int out_size, void* d_ws, size_t ws_size,
                              hipStream_t stream) {
    const float* obj     = (const float*)d_in[0];   // [4, 242991]
    const float* deltas  = (const float*)d_in[1];   // [4, 242991, 4]
    const float* anchors = (const float*)d_in[2];   // [242991, 4]
    float* out = (float*)d_out;                     // [4,1000,4] ++ [4,1000]

    char* ws = (char*)d_ws;
    unsigned*            hist    = (unsigned*)(ws);
    unsigned*            cnt     = (unsigned*)(ws + OFF_CNT);
    unsigned*            boxmax  = (unsigned*)(ws + OFF_BOXMAX);
    unsigned*            bar     = (unsigned*)(ws + OFF_BAR);
    unsigned long long*  cand    = (unsigned long long*)(ws + OFF_CAND);
    unsigned long long*  sel     = (unsigned long long*)(ws + OFF_SEL);
    float*               boxes_r = (float*)(ws + OFF_BOXR);
    float*               score_r = (float*)(ws + OFF_SCR);
    float*               boxes_l = (float*)(ws + OFF_BOXL);
    int*                 valid_l = (int*)(ws + OFF_VAL);
    int*                 rankmap = (int*)(ws + OFF_RMAP);
    int*                 keep_r  = (int*)(ws + OFF_KEEP);
    unsigned long long*  maskp   = (unsigned long long*)(ws + OFF_MASK);

    (void)in_sizes; (void)n_in; (void)out_size; (void)ws_size; (void)WS_NEED;

    // zero hist + cnt + boxmax + barrier counter (ws is poisoned 0xAA before every call)
    hipMemsetAsync(d_ws, 0, ZERO_BYTES, stream);

    k_fused<<<NBLK, BLKT, 0, stream>>>(
        obj, deltas, anchors, hist, cnt, boxmax, bar, cand, sel,
        boxes_r, score_r, boxes_l, valid_l, rankmap, keep_r, maskp, out);
}